// Round 8
// baseline (301.807 us; speedup 1.0000x reference)
//
#include <hip/hip_runtime.h>
#include <math.h>

#define BATCH 64
#define HIMG 224
#define WIMG 224
#define IMGPLANE (HIMG*WIMG)   // 50176
#define CF 512
#define HF 28
#define WF 28
#define POS (HF*WF)            // 784
#define ALPHA_C 0.15f
#define EPS_C 1e-6f

#define STRIPS 14              // 16-row strips per sample
#define SROWS 16
#define GROWS 20               // SROWS + 4 halo rows
#define GSTR 229               // LDS row stride for gray (odd)
#define VSTR 261               // LDS row stride for var (swizzled cols)

#define ZG 16                  // channel groups
#define ZCH 32                 // channels per group
#define NBPS (ZG + STRIPS)     // 30 producer blocks per sample

#define SHW 29                 // hres LDS row stride
#define SHN 6528               // 26,112 B: max(hres 224*29=6496, gray 4580, var 4176)

// ---- ws layout (in floats) ----
#define OFF_HRES 0
#define HRES_CNT (BATCH*HIMG*WF)             // 401,408
#define OFF_BMM (OFF_HRES + HRES_CNT)        // 403,200 after 64*14*2
#define OFF_AP  (OFF_BMM + BATCH*STRIPS*2)   // ZG*BATCH*POS partial sums
#define OFF_CNTS (OFF_AP + ZG*BATCH*POS)     // 64 per-sample done counters (uint)
#define OFF_ACC (OFF_CNTS + BATCH)           // loss accumulator
#define OFF_CNT (OFF_ACC + 1)                // global done counter (uint)

__global__ void init_k(float* ws) {
    int t = threadIdx.x;
    if (t < BATCH) ((unsigned*)ws)[OFF_CNTS + t] = 0u;
    if (t == BATCH) ws[OFF_ACC] = 0.0f;
    if (t == BATCH + 1) ((unsigned*)ws)[OFF_CNT] = 0u;
}

// One kernel: per sample b, 16 attn blocks + 14 varh blocks; the 30th
// finisher of sample b runs the fused (minmax/resize/MSE) stage for b.
__global__ __launch_bounds__(256) void mega_k(const float* __restrict__ img,
                                              const float* __restrict__ f,
                                              float* __restrict__ ws,
                                              float* __restrict__ out) {
    __shared__ float sh[SHN];      // gray -> var overlay (varh) / hres (fused)
    __shared__ float wred[8];
    __shared__ float s_mn, s_mx;
    __shared__ int s_last;
    int bid = blockIdx.x, tid = threadIdx.x;
    int b = bid / NBPS, r = bid - NBPS * b;

    if (r < ZG) {
        // -------- attn producer: 32 channels, float4, 2-ch pairing --------
        int z = r;
        if (tid < 196) {
            const float* fp = f + (size_t)(b * CF + z * ZCH) * POS + 4 * tid;
            float ax = 0, ay = 0, az = 0, aw = 0;
            float bx = 0, by = 0, bz = 0, bw = 0;
            #pragma unroll
            for (int c = 0; c < ZCH; c += 2) {
                float4 u = *(const float4*)(fp + (size_t)c * POS);
                float4 v = *(const float4*)(fp + (size_t)(c + 1) * POS);
                ax += u.x * u.x; ay += u.y * u.y; az += u.z * u.z; aw += u.w * u.w;
                bx += v.x * v.x; by += v.y * v.y; bz += v.z * v.z; bw += v.w * v.w;
            }
            *(float4*)(ws + OFF_AP + (size_t)(z * BATCH + b) * POS + 4 * tid) =
                make_float4(ax + bx, ay + by, az + bz, aw + bw);
        }
    } else {
        // -------- varh producer: gray -> 5x5 var -> horizontal resize --------
        int sy = r - ZG;
        int y0 = sy * SROWS;
        const float* imb = img + (size_t)b * 3 * IMGPLANE;

        for (int i = tid; i < GROWS * 56; i += 256) {
            int gr = i / 56, q = i - gr * 56;
            int gy = y0 - 2 + gr;
            float g0 = 0, g1 = 0, g2 = 0, g3 = 0;
            if ((unsigned)gy < HIMG) {
                const float* row = imb + gy * WIMG + 4 * q;
                float4 a = *(const float4*)(row);
                float4 bb = *(const float4*)(row + IMGPLANE);
                float4 c = *(const float4*)(row + 2 * IMGPLANE);
                g0 = 0.299f * a.x + 0.587f * bb.x + 0.114f * c.x;
                g1 = 0.299f * a.y + 0.587f * bb.y + 0.114f * c.y;
                g2 = 0.299f * a.z + 0.587f * bb.z + 0.114f * c.z;
                g3 = 0.299f * a.w + 0.587f * bb.w + 0.114f * c.w;
            }
            int base = gr * GSTR + 2 + 4 * q;
            sh[base] = g0; sh[base + 1] = g1; sh[base + 2] = g2; sh[base + 3] = g3;
        }
        if (tid < GROWS * 4) {
            int gr = tid >> 2, p = tid & 3;
            int gc = (p < 2) ? p : (224 + p);
            sh[gr * GSTR + gc] = 0.0f;
        }
        __syncthreads();

        int rr = tid >> 4, s = tid & 15;
        int x0 = 14 * s;
        const float* gr0 = sh + rr * GSTR;
        float c1[5], c2[5], vreg[14];
        #pragma unroll
        for (int m = 0; m < 5; m++) {
            float a = 0, a2 = 0;
            #pragma unroll
            for (int k = 0; k < 5; k++) {
                float u = gr0[k * GSTR + x0 + m];
                a += u; a2 += u * u;
            }
            c1[m] = a; c2[m] = a2;
        }
        float vmn = INFINITY, vmx = 0.0f;
        #pragma unroll
        for (int xi = 0; xi < 14; xi++) {
            int p = xi % 5;
            float s1 = c1[p], s2 = c2[p];
            #pragma unroll
            for (int m = 1; m < 5; m++) {
                s1 += c1[(p + m) % 5];
                s2 += c2[(p + m) % 5];
            }
            float m1 = s1 * 0.04f, m2 = s2 * 0.04f;
            float vv = fmaxf(m2 - m1 * m1, 0.0f);
            vreg[xi] = vv;
            vmn = fminf(vmn, vv); vmx = fmaxf(vmx, vv);
            if (xi < 13) {
                float a = 0, a2 = 0;
                #pragma unroll
                for (int k = 0; k < 5; k++) {
                    float u = gr0[k * GSTR + x0 + xi + 5];
                    a += u; a2 += u * u;
                }
                c1[p] = a; c2[p] = a2;
            }
        }
        #pragma unroll
        for (int o = 32; o > 0; o >>= 1) {
            vmn = fminf(vmn, __shfl_xor(vmn, o));
            vmx = fmaxf(vmx, __shfl_xor(vmx, o));
        }
        __syncthreads();   // gray reads done -> overlay var
        int w = tid >> 6;
        if ((tid & 63) == 0) { wred[w] = vmn; wred[4 + w] = vmx; }
        if (tid < SROWS * 8) {
            int r2 = tid >> 3, p = tid & 7;
            int jh = p + ((p < 4) ? 0 : 224);
            sh[r2 * VSTR + jh + (jh >> 3)] = 0.0f;
        }
        #pragma unroll
        for (int xi = 0; xi < 14; xi++) {
            int jh = x0 + xi + 4;
            sh[rr * VSTR + jh + (jh >> 3)] = vreg[xi];
        }
        __syncthreads();
        if (tid == 0) {
            float mn = fminf(fminf(wred[0], wred[1]), fminf(wred[2], wred[3]));
            float mx = fmaxf(fmaxf(wred[4], wred[5]), fmaxf(wred[6], wred[7]));
            int blk = b * STRIPS + sy;
            ws[OFF_BMM + 2 * blk]     = mn;
            ws[OFF_BMM + 2 * blk + 1] = mx;
        }
        float* hb = ws + OFF_HRES + ((size_t)b * HIMG + y0) * WF;
        for (int idx = tid; idx < SROWS * WF; idx += 256) {
            int r3 = idx / WF, i = idx - r3 * WF;
            float acc = 0.0f, wsum = 0.0f;
            int j0 = 8 * i - 4;
            #pragma unroll
            for (int t = 0; t < 16; t++) {
                int j = j0 + t;
                float w_ = 8.0f - fabsf((float)t - 7.5f);
                int jh = j + 4;
                acc += w_ * sh[r3 * VSTR + jh + (jh >> 3)];
                if ((unsigned)j < WIMG) wsum += w_;
            }
            hb[idx] = acc / wsum;
        }
    }

    // -------- completion: 30th finisher of sample b runs the fused stage --------
    __syncthreads();
    if (tid == 0) {
        __threadfence();   // publish this block's global stores device-wide
        unsigned old = atomicAdd((unsigned*)ws + OFF_CNTS + b, 1u);
        s_last = (old == NBPS - 1) ? 1 : 0;
    }
    __syncthreads();
    if (!s_last) return;
    __threadfence();       // acquire: see all 30 producers' data

    // 1) reduce 14 per-strip var min/max
    if (tid < 64) {
        float mn = INFINITY, mx = 0.0f;
        if (tid < STRIPS) {
            mn = ws[OFF_BMM + 2 * (b * STRIPS + tid)];
            mx = ws[OFF_BMM + 2 * (b * STRIPS + tid) + 1];
        }
        #pragma unroll
        for (int o = 8; o > 0; o >>= 1) {
            mn = fminf(mn, __shfl_down(mn, o));
            mx = fmaxf(mx, __shfl_down(mx, o));
        }
        if (tid == 0) { s_mn = mn; s_mx = mx; }
    }
    // 2) stage hres into sh (overlay ok: producer sh reads are done)
    const float* hg = ws + OFF_HRES + (size_t)b * HIMG * WF;
    for (int i = tid; i < HIMG * WF; i += 256) {
        int y = i / WF, x = i - y * WF;
        sh[y * SHW + x] = hg[i];
    }
    __syncthreads();

    float vmn = s_mn, vmx = s_mx;
    float vden = vmx - vmn;
    bool vok = vden > EPS_C;

    // 3) vertical resize -> sal; attn from ZG partials
    const float* ap = ws + OFF_AP + (size_t)b * POS;
    float salv[4], attnv[4];
    float amn = INFINITY, amx = -INFINITY;
    #pragma unroll
    for (int k = 0; k < 4; k++) {
        int idx = tid + 256 * k;
        salv[k] = 0.0f; attnv[k] = 0.0f;
        if (idx < POS) {
            int yo = idx / WF, x = idx - yo * WF;
            float acc = 0.0f, wsum = 0.0f;
            int j0 = 8 * yo - 4;
            #pragma unroll
            for (int t = 0; t < 16; t++) {
                int j = j0 + t;
                float w = 8.0f - fabsf((float)t - 7.5f);
                if ((unsigned)j < HIMG) { acc += w * sh[j * SHW + x]; wsum += w; }
            }
            float sraw = acc / wsum;
            salv[k] = vok ? (sraw - vmn) / vden : 0.5f;
            float ssum = 0.0f;
            #pragma unroll
            for (int z = 0; z < ZG; z++)
                ssum += ap[(size_t)z * BATCH * POS + idx];
            float a = sqrtf(ssum * (1.0f / CF));
            attnv[k] = a;
            amn = fminf(amn, a); amx = fmaxf(amx, a);
        }
    }

    // 4) block min/max of attn
    #pragma unroll
    for (int o = 32; o > 0; o >>= 1) {
        amn = fminf(amn, __shfl_xor(amn, o));
        amx = fmaxf(amx, __shfl_xor(amx, o));
    }
    int w = tid >> 6;
    if ((tid & 63) == 0) wred[w] = amn;
    __syncthreads();
    if (tid == 0) s_mn = fminf(fminf(wred[0], wred[1]), fminf(wred[2], wred[3]));
    __syncthreads();
    if ((tid & 63) == 0) wred[w] = amx;
    __syncthreads();
    if (tid == 0) s_mx = fmaxf(fmaxf(wred[0], wred[1]), fmaxf(wred[2], wred[3]));
    __syncthreads();
    amn = s_mn; amx = s_mx;
    float aden = amx - amn;
    bool aok = aden > EPS_C;

    // 5) MSE partial
    float lsum = 0.0f;
    #pragma unroll
    for (int k = 0; k < 4; k++) {
        int idx = tid + 256 * k;
        if (idx < POS) {
            float an = aok ? (attnv[k] - amn) / aden : 0.5f;
            float d = an - salv[k];
            lsum += d * d;
        }
    }
    #pragma unroll
    for (int o = 32; o > 0; o >>= 1) lsum += __shfl_xor(lsum, o);
    if ((tid & 63) == 0) wred[w] = lsum;
    __syncthreads();

    // 6) accumulate; last of 64 fused finishers writes the output
    if (tid == 0) {
        float part = wred[0] + wred[1] + wred[2] + wred[3];
        atomicAdd(ws + OFF_ACC, part);
        __threadfence();
        unsigned old = atomicAdd((unsigned*)ws + OFF_CNT, 1u);
        if (old == BATCH - 1) {
            float tot = atomicAdd(ws + OFF_ACC, 0.0f);  // device-coherent read
            out[0] = tot * (ALPHA_C / (float)(BATCH * POS));
        }
    }
}

extern "C" void kernel_launch(void* const* d_in, const int* in_sizes, int n_in,
                              void* d_out, int out_size, void* d_ws, size_t ws_size,
                              hipStream_t stream) {
    const float* features = (const float*)d_in[0];  // [64,512,28,28]
    const float* images   = (const float*)d_in[1];  // [64,3,224,224]
    float* ws  = (float*)d_ws;
    float* out = (float*)d_out;

    hipLaunchKernelGGL(init_k, dim3(1),             dim3(256), 0, stream, ws);
    hipLaunchKernelGGL(mega_k, dim3(BATCH * NBPS),  dim3(256), 0, stream,
                       images, features, ws, out);
}